// Round 2
// baseline (590.629 us; speedup 1.0000x reference)
//
#include <hip/hip_runtime.h>

// Problem constants
// B=32, F=128, T=2048, HID=256, NC=64, A=15, node=128

typedef float f32x4 __attribute__((ext_vector_type(4)));
typedef unsigned short u16x8 __attribute__((ext_vector_type(8)));

__device__ inline float b2f(unsigned short u) {
  return __uint_as_float(((unsigned int)u) << 16);
}
__device__ inline unsigned short f2b(float f) {
  unsigned int u = __float_as_uint(f);
  unsigned int r = u + 0x7fffu + ((u >> 16) & 1u);
  return (unsigned short)(r >> 16);
}
__device__ inline float h2f(unsigned short u) {
  return (float)__builtin_bit_cast(_Float16, u);
}
__device__ inline unsigned short f2h(float f) {
  return __builtin_bit_cast(unsigned short, (_Float16)f);
}
__device__ inline float leaky(float v) { return v >= 0.f ? v : 0.2f * v; }

// ---------------- K1: XW1[b*128+f][h] = (x @ W1), bf16 out ----------------
// M=4096, N=256, K=2048. 64x64 tile/block, 4x4 per thread, A stored transposed.
__global__ __launch_bounds__(256) void k_xw1(const float* __restrict__ x,
                                             const float* __restrict__ W1,
                                             unsigned short* __restrict__ XW1) {
  __shared__ float As[32][68];  // [k][row]
  __shared__ float Bs[32][68];  // [k][col]
  const int tid = threadIdx.x;
  const int tx = tid & 15, ty = tid >> 4;
  const int row0 = blockIdx.y * 64;
  const int col0 = blockIdx.x * 64;
  float acc[4][4] = {};
  for (int k0 = 0; k0 < 2048; k0 += 32) {
#pragma unroll
    for (int it = 0; it < 2; ++it) {
      int f4 = tid + it * 256;        // 512 float4 of A tile
      int rr = f4 >> 3;               // 0..63
      int cc = (f4 & 7) << 2;         // 0..28
      f32x4 v = *reinterpret_cast<const f32x4*>(&x[(size_t)(row0 + rr) * 2048 + k0 + cc]);
      As[cc + 0][rr] = v[0];
      As[cc + 1][rr] = v[1];
      As[cc + 2][rr] = v[2];
      As[cc + 3][rr] = v[3];
    }
#pragma unroll
    for (int it = 0; it < 2; ++it) {
      int f4 = tid + it * 256;        // 512 float4 of B tile
      int rr = f4 >> 4;               // 0..31
      int cc = (f4 & 15) << 2;        // 0..60
      f32x4 v = *reinterpret_cast<const f32x4*>(&W1[(size_t)(k0 + rr) * 256 + col0 + cc]);
      *reinterpret_cast<f32x4*>(&Bs[rr][cc]) = v;
    }
    __syncthreads();
#pragma unroll
    for (int kk = 0; kk < 32; ++kk) {
      f32x4 a4 = *reinterpret_cast<const f32x4*>(&As[kk][ty * 4]);
      f32x4 b4 = *reinterpret_cast<const f32x4*>(&Bs[kk][tx * 4]);
#pragma unroll
      for (int r = 0; r < 4; ++r)
#pragma unroll
        for (int c = 0; c < 4; ++c) acc[r][c] += a4[r] * b4[c];
    }
    __syncthreads();
  }
#pragma unroll
  for (int r = 0; r < 4; ++r)
#pragma unroll
    for (int c = 0; c < 4; ++c)
      XW1[(size_t)(row0 + ty * 4 + r) * 256 + col0 + tx * 4 + c] = f2b(acc[r][c]);
}

// ---------------- K2: per-(b,a) fused chain ----------------
// grid = 480 (b*15+a), 256 threads. LDS budget ~139 KB -> 1 block/CU.
__global__ __launch_bounds__(256) void k_chain(
    const float* __restrict__ x, const unsigned short* __restrict__ XW1,
    const float* __restrict__ b1g, const float* __restrict__ W2,
    const float* __restrict__ b2g, const float* __restrict__ W3,
    const float* __restrict__ b3g, float* __restrict__ gXa) {
  __shared__ unsigned short sAdj[128 * 136];  // fp16 adj (symmetric)
  __shared__ unsigned short sP[128 * 136];    // bf16: u2a -> h2a -> u3
  __shared__ unsigned short sR[128 * 264];    // fp32 win -> bf16 h1 -> u2b|h2b -> fp32 xa
  __shared__ float sSum[128];
  __shared__ float sDiag[128];
  __shared__ float sDinv[128];

  const int tid = threadIdx.x;
  const int ig = tid >> 3;  // 0..31
  const int jg = tid & 7;   // 0..7
  const int i0 = ig * 4;
  const int b = blockIdx.x / 15;
  const int a = blockIdx.x % 15;

  float* winf = reinterpret_cast<float*>(sR);  // [128][128] fp32

  // ---- phase 0: load window + column sums ----
  const float* xb = x + (size_t)b * 128 * 2048 + a * 128;
#pragma unroll
  for (int it = 0; it < 16; ++it) {
    int e4 = tid + it * 256;
    int f = e4 >> 5;
    int j = (e4 & 31) << 2;
    *reinterpret_cast<f32x4*>(&winf[f * 128 + j]) =
        *reinterpret_cast<const f32x4*>(&xb[(size_t)f * 2048 + j]);
  }
  __syncthreads();
  if (tid < 128) {
    float s = 0.f;
    for (int f = 0; f < 128; ++f) s += winf[f * 128 + tid];
    sSum[tid] = s;
  }
  __syncthreads();

  // ---- phase 1: c = win^T win (centered), adj = (clip(corr)+1)/2 ----
  {
    const int j0 = jg * 16;
    float acc[4][16] = {};
    for (int f = 0; f < 128; ++f) {
      const float* row = &winf[f * 128];
      f32x4 a4 = *reinterpret_cast<const f32x4*>(row + i0);
      float bv[16];
#pragma unroll
      for (int q = 0; q < 4; ++q)
        *reinterpret_cast<f32x4*>(&bv[q * 4]) =
            *reinterpret_cast<const f32x4*>(row + j0 + q * 4);
#pragma unroll
      for (int r = 0; r < 4; ++r) {
        float av = a4[r];
#pragma unroll
        for (int c = 0; c < 16; ++c) acc[r][c] += av * bv[c];
      }
    }
    const float inv128 = 1.f / 128.f;
#pragma unroll
    for (int r = 0; r < 4; ++r) {
      float si = sSum[i0 + r];
#pragma unroll
      for (int c = 0; c < 16; ++c) acc[r][c] -= si * sSum[j0 + c] * inv128;
    }
#pragma unroll
    for (int r = 0; r < 4; ++r) {
      int i = i0 + r;
      if (i >= j0 && i < j0 + 16) sDiag[i] = acc[r][i - j0];
    }
    __syncthreads();
    if (tid < 128) {
      float d = sDiag[tid];
      sDinv[tid] = d > 0.f ? (1.f / sqrtf(d)) : 0.f;
    }
    __syncthreads();
#pragma unroll
    for (int r = 0; r < 4; ++r) {
      float di = sDinv[i0 + r];
#pragma unroll
      for (int c = 0; c < 16; ++c) {
        float dj = sDinv[j0 + c];
        float v = acc[r][c] * di * dj;
        v = fminf(1.f, fmaxf(-1.f, v));
        v = 0.5f * v + 0.5f;
        if (di == 0.f || dj == 0.f) v = 0.f;  // nan_to_num
        sAdj[(i0 + r) * 136 + j0 + c] = f2h(v);
      }
    }
  }
  __syncthreads();

  // ---- phase 2: h1 = leaky(adj @ XW1b + b1) -> sR bf16 [128][256] ----
  {
    const unsigned short* XWb = XW1 + (size_t)b * 128 * 256;
    const int j0 = jg * 16;
#pragma unroll 1
    for (int n0 = 0; n0 < 256; n0 += 128) {
      float acc[4][16] = {};
      for (int k0 = 0; k0 < 128; k0 += 8) {
        u16x8 af[4];
#pragma unroll
        for (int r = 0; r < 4; ++r)
          af[r] = *reinterpret_cast<const u16x8*>(&sAdj[(i0 + r) * 136 + k0]);
#pragma unroll
        for (int kk = 0; kk < 8; ++kk) {
          u16x8 u0 = *reinterpret_cast<const u16x8*>(&XWb[(size_t)(k0 + kk) * 256 + n0 + j0]);
          u16x8 u1 = *reinterpret_cast<const u16x8*>(&XWb[(size_t)(k0 + kk) * 256 + n0 + j0 + 8]);
          float bv[16];
#pragma unroll
          for (int q = 0; q < 8; ++q) { bv[q] = b2f(u0[q]); bv[8 + q] = b2f(u1[q]); }
#pragma unroll
          for (int r = 0; r < 4; ++r) {
            float av = h2f(af[r][kk]);
#pragma unroll
            for (int c = 0; c < 16; ++c) acc[r][c] += av * bv[c];
          }
        }
      }
#pragma unroll
      for (int r = 0; r < 4; ++r)
#pragma unroll
        for (int c = 0; c < 16; ++c) {
          float v = leaky(acc[r][c] + b1g[n0 + j0 + c]);
          sR[(i0 + r) * 264 + n0 + j0 + c] = f2b(v);
        }
    }
  }
  __syncthreads();

  // ---- phase 3a: u2a = h1 @ W2[:,0:128] -> sP ----
  {
    const int j0 = jg * 16;
    float acc[4][16] = {};
    for (int k0 = 0; k0 < 256; k0 += 8) {
      u16x8 af[4];
#pragma unroll
      for (int r = 0; r < 4; ++r)
        af[r] = *reinterpret_cast<const u16x8*>(&sR[(i0 + r) * 264 + k0]);
#pragma unroll
      for (int kk = 0; kk < 8; ++kk) {
        float bv[16];
#pragma unroll
        for (int q = 0; q < 4; ++q)
          *reinterpret_cast<f32x4*>(&bv[q * 4]) =
              *reinterpret_cast<const f32x4*>(&W2[(size_t)(k0 + kk) * 256 + j0 + q * 4]);
#pragma unroll
        for (int r = 0; r < 4; ++r) {
          float av = b2f(af[r][kk]);
#pragma unroll
          for (int c = 0; c < 16; ++c) acc[r][c] += av * bv[c];
        }
      }
    }
#pragma unroll
    for (int r = 0; r < 4; ++r)
#pragma unroll
      for (int c = 0; c < 16; ++c)
        sP[(i0 + r) * 136 + j0 + c] = f2b(acc[r][c]);
  }
  __syncthreads();

  // ---- phase 3b: h2a = leaky(adj @ u2a + b2[0:128]) -> sP in-place ----
  {
    const int j0 = jg * 16;
    float acc[4][16] = {};
    for (int k0 = 0; k0 < 128; k0 += 8) {
      u16x8 af[4];
#pragma unroll
      for (int r = 0; r < 4; ++r)
        af[r] = *reinterpret_cast<const u16x8*>(&sAdj[(i0 + r) * 136 + k0]);
#pragma unroll
      for (int kk = 0; kk < 8; ++kk) {
        u16x8 u0 = *reinterpret_cast<const u16x8*>(&sP[(k0 + kk) * 136 + j0]);
        u16x8 u1 = *reinterpret_cast<const u16x8*>(&sP[(k0 + kk) * 136 + j0 + 8]);
        float bv[16];
#pragma unroll
        for (int q = 0; q < 8; ++q) { bv[q] = b2f(u0[q]); bv[8 + q] = b2f(u1[q]); }
#pragma unroll
        for (int r = 0; r < 4; ++r) {
          float av = h2f(af[r][kk]);
#pragma unroll
          for (int c = 0; c < 16; ++c) acc[r][c] += av * bv[c];
        }
      }
    }
    __syncthreads();  // all u2a reads done before overwrite
#pragma unroll
    for (int r = 0; r < 4; ++r)
#pragma unroll
      for (int c = 0; c < 16; ++c)
        sP[(i0 + r) * 136 + j0 + c] = f2b(leaky(acc[r][c] + b2g[j0 + c]));
  }
  __syncthreads();

  // ---- phase 3c: u2b = h1 @ W2[:,128:256] -> sR cols 0..127 (over h1) ----
  {
    const int j0 = jg * 16;
    float acc[4][16] = {};
    for (int k0 = 0; k0 < 256; k0 += 8) {
      u16x8 af[4];
#pragma unroll
      for (int r = 0; r < 4; ++r)
        af[r] = *reinterpret_cast<const u16x8*>(&sR[(i0 + r) * 264 + k0]);
#pragma unroll
      for (int kk = 0; kk < 8; ++kk) {
        float bv[16];
#pragma unroll
        for (int q = 0; q < 4; ++q)
          *reinterpret_cast<f32x4*>(&bv[q * 4]) =
              *reinterpret_cast<const f32x4*>(&W2[(size_t)(k0 + kk) * 256 + 128 + j0 + q * 4]);
#pragma unroll
        for (int r = 0; r < 4; ++r) {
          float av = b2f(af[r][kk]);
#pragma unroll
          for (int c = 0; c < 16; ++c) acc[r][c] += av * bv[c];
        }
      }
    }
    __syncthreads();  // all h1 reads done before overwrite
#pragma unroll
    for (int r = 0; r < 4; ++r)
#pragma unroll
      for (int c = 0; c < 16; ++c)
        sR[(i0 + r) * 264 + j0 + c] = f2b(acc[r][c]);
  }
  __syncthreads();

  // ---- phase 3d: h2b = leaky(adj @ u2b + b2[128:256]) -> sR cols 128..255 ----
  {
    const int j0 = jg * 16;
    float acc[4][16] = {};
    for (int k0 = 0; k0 < 128; k0 += 8) {
      u16x8 af[4];
#pragma unroll
      for (int r = 0; r < 4; ++r)
        af[r] = *reinterpret_cast<const u16x8*>(&sAdj[(i0 + r) * 136 + k0]);
#pragma unroll
      for (int kk = 0; kk < 8; ++kk) {
        u16x8 u0 = *reinterpret_cast<const u16x8*>(&sR[(k0 + kk) * 264 + j0]);
        u16x8 u1 = *reinterpret_cast<const u16x8*>(&sR[(k0 + kk) * 264 + j0 + 8]);
        float bv[16];
#pragma unroll
        for (int q = 0; q < 8; ++q) { bv[q] = b2f(u0[q]); bv[8 + q] = b2f(u1[q]); }
#pragma unroll
        for (int r = 0; r < 4; ++r) {
          float av = h2f(af[r][kk]);
#pragma unroll
          for (int c = 0; c < 16; ++c) acc[r][c] += av * bv[c];
        }
      }
    }
    // writes (cols 128..255) don't alias u2b (cols 0..127): no pre-barrier needed
#pragma unroll
    for (int r = 0; r < 4; ++r)
#pragma unroll
      for (int c = 0; c < 16; ++c)
        sR[(i0 + r) * 264 + 128 + j0 + c] = f2b(leaky(acc[r][c] + b2g[128 + j0 + c]));
  }
  __syncthreads();

  // ---- phase 4: u3 = h2 @ W3 -> sP cols 0..63 ----
  {
    const int j0 = jg * 8;
    float acc[4][8] = {};
    for (int k0 = 0; k0 < 256; k0 += 8) {
      u16x8 af[4];
#pragma unroll
      for (int r = 0; r < 4; ++r)
        af[r] = (k0 < 128)
                    ? *reinterpret_cast<const u16x8*>(&sP[(i0 + r) * 136 + k0])
                    : *reinterpret_cast<const u16x8*>(&sR[(i0 + r) * 264 + k0]);
#pragma unroll
      for (int kk = 0; kk < 8; ++kk) {
        float bv[8];
#pragma unroll
        for (int q = 0; q < 2; ++q)
          *reinterpret_cast<f32x4*>(&bv[q * 4]) =
              *reinterpret_cast<const f32x4*>(&W3[(size_t)(k0 + kk) * 64 + j0 + q * 4]);
#pragma unroll
        for (int r = 0; r < 4; ++r) {
          float av = b2f(af[r][kk]);
#pragma unroll
          for (int c = 0; c < 8; ++c) acc[r][c] += av * bv[c];
        }
      }
    }
    __syncthreads();  // h2a reads done before overwrite
#pragma unroll
    for (int r = 0; r < 4; ++r)
#pragma unroll
      for (int c = 0; c < 8; ++c)
        sP[(i0 + r) * 136 + j0 + c] = f2b(acc[r][c]);
  }
  __syncthreads();

  // ---- phase 5: xa = leaky(adj @ u3 + b3) -> fp32 [128][68] in sR; mean ----
  {
    const int j0 = jg * 8;
    float acc[4][8] = {};
    for (int k0 = 0; k0 < 128; k0 += 8) {
      u16x8 af[4];
#pragma unroll
      for (int r = 0; r < 4; ++r)
        af[r] = *reinterpret_cast<const u16x8*>(&sAdj[(i0 + r) * 136 + k0]);
#pragma unroll
      for (int kk = 0; kk < 8; ++kk) {
        u16x8 u0 = *reinterpret_cast<const u16x8*>(&sP[(k0 + kk) * 136 + j0]);
        float bv[8];
#pragma unroll
        for (int q = 0; q < 8; ++q) bv[q] = b2f(u0[q]);
#pragma unroll
        for (int r = 0; r < 4; ++r) {
          float av = h2f(af[r][kk]);
#pragma unroll
          for (int c = 0; c < 8; ++c) acc[r][c] += av * bv[c];
        }
      }
    }
    float* xaf = reinterpret_cast<float*>(sR);  // sR fully dead (last read phase 4)
#pragma unroll
    for (int r = 0; r < 4; ++r)
#pragma unroll
      for (int c = 0; c < 8; ++c)
        xaf[(i0 + r) * 68 + j0 + c] = leaky(acc[r][c] + b3g[j0 + c]);
  }
  __syncthreads();
  if (tid < 64) {
    const float* xaf = reinterpret_cast<const float*>(sR);
    float s = 0.f;
    for (int i = 0; i < 128; ++i) s += xaf[i * 68 + tid];
    gXa[((size_t)b * 15 + a) * 64 + tid] = s * (1.f / 128.f);
  }
}

// ---------------- K3: per-batch head ----------------
__global__ __launch_bounds__(256) void k_head(const float* __restrict__ gXa,
                                              const float* __restrict__ W4,
                                              const float* __restrict__ b4,
                                              float* __restrict__ out) {
  __shared__ float xb[15 * 64];
  __shared__ float c2[15 * 16];
  __shared__ float mu[15];
  __shared__ float dinv[15];
  __shared__ float yy[15 * 64];
  __shared__ float zz[15 * 64];
  const int b = blockIdx.x;
  const int tid = threadIdx.x;
  for (int e = tid; e < 960; e += 256) xb[e] = gXa[(size_t)b * 960 + e];
  __syncthreads();
  if (tid < 15) {
    float s = 0.f;
    for (int c = 0; c < 64; ++c) s += xb[tid * 64 + c];
    mu[tid] = s * (1.f / 64.f);
  }
  __syncthreads();
  if (tid < 225) {
    int p = tid / 15, q = tid % 15;
    float s = 0.f;
    for (int c = 0; c < 64; ++c)
      s += (xb[p * 64 + c] - mu[p]) * (xb[q * 64 + c] - mu[q]);
    c2[p * 16 + q] = s;
  }
  __syncthreads();
  if (tid < 15) {
    float d = c2[tid * 16 + tid];
    dinv[tid] = d > 0.f ? (1.f / sqrtf(d)) : 0.f;
  }
  __syncthreads();
  if (tid < 225) {
    int p = tid / 15, q = tid % 15;
    float v = c2[p * 16 + q] * dinv[p] * dinv[q];
    v = fminf(1.f, fmaxf(-1.f, v));
    if (dinv[p] == 0.f || dinv[q] == 0.f) v = 0.f;
    c2[p * 16 + q] = v;
  }
  __syncthreads();
  for (int e = tid; e < 960; e += 256) {
    int p = e >> 6, c = e & 63;
    float s = 0.f;
    for (int q = 0; q < 15; ++q) s += c2[p * 16 + q] * xb[q * 64 + c];
    yy[e] = s;
  }
  __syncthreads();
  for (int e = tid; e < 960; e += 256) {
    int p = e >> 6, c = e & 63;
    float s = b4[c];
    for (int k = 0; k < 64; ++k) s += yy[p * 64 + k] * W4[k * 64 + c];
    zz[e] = leaky(s);
  }
  __syncthreads();
  if (tid < 64) {
    float m = -INFINITY;
    for (int p = 0; p < 15; ++p) m = fmaxf(m, zz[p * 64 + tid]);
    out[(size_t)b * 64 + tid] = m;
  }
}

extern "C" void kernel_launch(void* const* d_in, const int* in_sizes, int n_in,
                              void* d_out, int out_size, void* d_ws, size_t ws_size,
                              hipStream_t stream) {
  const float* x  = (const float*)d_in[0];
  const float* W1 = (const float*)d_in[1];
  const float* b1 = (const float*)d_in[2];
  const float* W2 = (const float*)d_in[3];
  const float* b2 = (const float*)d_in[4];
  const float* W3 = (const float*)d_in[5];
  const float* b3 = (const float*)d_in[6];
  const float* W4 = (const float*)d_in[7];
  const float* b4 = (const float*)d_in[8];
  float* out = (float*)d_out;

  unsigned short* XW1 = (unsigned short*)d_ws;                    // 4096*256 bf16 = 2 MB
  float* gXa = (float*)((char*)d_ws + (size_t)4096 * 256 * 2);    // 32*15*64 fp32

  dim3 g1(4, 64);
  k_xw1<<<g1, 256, 0, stream>>>(x, W1, XW1);
  k_chain<<<480, 256, 0, stream>>>(x, XW1, b1, W2, b2, W3, b3, gXa);
  k_head<<<32, 256, 0, stream>>>(gXa, W4, b4, out);
}

// Round 3
// 184.725 us; speedup vs baseline: 3.1973x; 3.1973x over previous
//
#include <hip/hip_runtime.h>

// B=32, F=node=128, T=2048, HID=256, NC=64, A=15 windows
// Chain per (b,a): adj=corrcoef window; h1=leaky(adj@XW1+b1);
// u2=h1@W2; h2=leaky(adj@u2+b2); u3=h2@W3; xa=leaky(adj@u3+b3); mean rows.
// Weight-side GEMMs computed swapped (W^T @ h^T) so outputs land in B^T layout.

typedef float f32x4 __attribute__((ext_vector_type(4)));
typedef __bf16 bf16x8 __attribute__((ext_vector_type(8)));
typedef unsigned short u16x4 __attribute__((ext_vector_type(4)));

__device__ inline unsigned short f2b(float f) {
  unsigned int u = __float_as_uint(f);
  unsigned int r = u + 0x7fffu + ((u >> 16) & 1u);
  return (unsigned short)(r >> 16);
}
__device__ inline float b2f(unsigned short u) {
  return __uint_as_float(((unsigned int)u) << 16);
}
__device__ inline float leaky(float v) { return v >= 0.f ? v : 0.2f * v; }

// XOR swizzle on element index (16B granularity) to kill 256B/512B-row bank conflicts
#define SWZ(k, r) ((k) ^ (((r) & 7) << 3))

// ---------------- k_prep: transpose W1/W2/W3 to bf16 (row = out-feature) ----------------
__global__ __launch_bounds__(256) void k_prep(const float* __restrict__ W1,
                                              const float* __restrict__ W2,
                                              const float* __restrict__ W3,
                                              unsigned short* __restrict__ W1T,
                                              unsigned short* __restrict__ W2T,
                                              unsigned short* __restrict__ W3T) {
  __shared__ float t[64][65];
  const int bid = blockIdx.x;
  const float* src;
  unsigned short* dst;
  int K, N, k0, n0;
  if (bid < 128) {        // W1 [2048][256] -> W1T [256][2048]
    src = W1; dst = W1T; K = 2048; N = 256;
    k0 = (bid >> 2) * 64; n0 = (bid & 3) * 64;
  } else if (bid < 144) { // W2 [256][256] -> W2T [256][256]
    src = W2; dst = W2T; K = 256; N = 256;
    int i = bid - 128; k0 = (i >> 2) * 64; n0 = (i & 3) * 64;
  } else {                // W3 [256][64] -> W3T [64][256]
    src = W3; dst = W3T; K = 256; N = 64;
    int i = bid - 144; k0 = i * 64; n0 = 0;
  }
  const int tid = threadIdx.x;
#pragma unroll
  for (int it = 0; it < 16; ++it) {
    int e = tid + it * 256, r = e >> 6, c = e & 63;
    t[r][c] = src[(size_t)(k0 + r) * N + n0 + c];
  }
  __syncthreads();
#pragma unroll
  for (int it = 0; it < 16; ++it) {
    int e = tid + it * 256, rr = e >> 6, cc = e & 63;
    dst[(size_t)(n0 + rr) * K + k0 + cc] = f2b(t[cc][rr]);
  }
}

// ---------------- k_xw1: XW1T[b][hid=256][f=128] = (x_b @ W1)^T via MFMA ----------------
__global__ __launch_bounds__(512) void k_xw1(const float* __restrict__ x,
                                             const unsigned short* __restrict__ W1T,
                                             unsigned short* __restrict__ XW1T) {
  __shared__ __align__(16) unsigned short sX[128 * 64];  // x tile [f][64] bf16 swz
  const int tid = threadIdx.x;
  const int w = tid >> 6, lane = tid & 63;
  const int l15 = lane & 15, l4 = lane >> 4;
  const int b = blockIdx.x;
  const float* xb = x + (size_t)b * 128 * 2048;
  const int m0 = w * 32;
  f32x4 acc[2][8] = {};
  for (int kb = 0; kb < 2048; kb += 64) {
    __syncthreads();  // previous MFMA reads done before overwrite
#pragma unroll
    for (int it = 0; it < 4; ++it) {
      int e4 = tid + it * 512;         // 2048 float4 = 8192 elems
      int f = e4 >> 4;                 // 0..127
      int k4 = (e4 & 15) << 2;         // 0..60
      f32x4 v = *(const f32x4*)&xb[(size_t)f * 2048 + kb + k4];
      u16x4 s;
      s[0] = f2b(v[0]); s[1] = f2b(v[1]); s[2] = f2b(v[2]); s[3] = f2b(v[3]);
      *(u16x4*)&sX[f * 64 + SWZ(k4, f)] = s;
    }
    __syncthreads();
#pragma unroll
    for (int ks = 0; ks < 2; ++ks) {
      bf16x8 bfr[8];
#pragma unroll
      for (int nt = 0; nt < 8; ++nt) {
        int br = nt * 16 + l15;
        bfr[nt] = *(const bf16x8*)&sX[br * 64 + SWZ(ks * 32 + l4 * 8, br)];
      }
#pragma unroll
      for (int mt = 0; mt < 2; ++mt) {
        bf16x8 af = *(const bf16x8*)&W1T[(size_t)(m0 + mt * 16 + l15) * 2048 + kb + ks * 32 + l4 * 8];
#pragma unroll
        for (int nt = 0; nt < 8; ++nt)
          acc[mt][nt] = __builtin_amdgcn_mfma_f32_16x16x32_bf16(af, bfr[nt], acc[mt][nt], 0, 0, 0);
      }
    }
  }
  unsigned short* dst = XW1T + (size_t)b * 256 * 128;
#pragma unroll
  for (int mt = 0; mt < 2; ++mt)
#pragma unroll
    for (int nt = 0; nt < 8; ++nt)
#pragma unroll
      for (int r = 0; r < 4; ++r) {
        int p = m0 + mt * 16 + l4 * 4 + r;  // hid
        int f = nt * 16 + l15;              // node/f
        dst[p * 128 + f] = f2b(acc[mt][nt][r]);
      }
}

// ---------------- k_chain: per-(b,a) fused MFMA chain, 512 thr, 160K LDS ----------------
__global__ __launch_bounds__(512) void k_chain(
    const float* __restrict__ x, const unsigned short* __restrict__ XW1T,
    const unsigned short* __restrict__ W2T, const unsigned short* __restrict__ W3T,
    const float* __restrict__ b1g, const float* __restrict__ b2g,
    const float* __restrict__ b3g, float* __restrict__ gXa) {
  __shared__ __align__(16) unsigned short sAdj[128 * 128];   // 32 KB
  __shared__ __align__(16) unsigned short sBufA[128 * 256];  // 64 KB: winT -> h1 -> h2
  __shared__ __align__(16) unsigned short sBufB[128 * 256];  // 64 KB: sums -> u2T -> u3T|xa

  const int tid = threadIdx.x;
  const int w = tid >> 6, lane = tid & 63;
  const int l15 = lane & 15, l4 = lane >> 4;
  const int b = blockIdx.x / 15, a = blockIdx.x % 15;
  float* fS = reinterpret_cast<float*>(sBufB);  // [0:128) sum, [128:256) diag, [256:384) dinv

  // ---- phase 0: window -> winT[j][f] bf16 swz in sBufA; row sums ----
  const float* xb = x + (size_t)b * 128 * 2048 + (size_t)a * 128;
#pragma unroll
  for (int it = 0; it < 8; ++it) {
    int e4 = tid + it * 512;
    int f = e4 >> 5;                // 0..127
    int j4 = (e4 & 31) << 2;        // 0..124
    f32x4 v = *(const f32x4*)&xb[(size_t)f * 2048 + j4];
#pragma unroll
    for (int q = 0; q < 4; ++q) {
      int r = j4 + q;
      sBufA[r * 128 + SWZ(f, r)] = f2b(v[q]);
    }
  }
  __syncthreads();
  if (tid < 128) {
    float s = 0.f;
    for (int t = 0; t < 128; ++t) s += b2f(sBufA[tid * 128 + t]);  // full row, any order
    fS[tid] = s;
  }
  __syncthreads();

  // ---- syrk: c = winT @ winT^T (MFMA), center, scale -> sAdj bf16 ----
  {
    f32x4 acc[8] = {};
    const int m0 = w * 16;
#pragma unroll
    for (int ks = 0; ks < 4; ++ks) {
      int ar = m0 + l15;
      bf16x8 af = *(const bf16x8*)&sBufA[ar * 128 + SWZ(ks * 32 + l4 * 8, ar)];
#pragma unroll
      for (int nt = 0; nt < 8; ++nt) {
        int br = nt * 16 + l15;
        bf16x8 bf = *(const bf16x8*)&sBufA[br * 128 + SWZ(ks * 32 + l4 * 8, br)];
        acc[nt] = __builtin_amdgcn_mfma_f32_16x16x32_bf16(af, bf, acc[nt], 0, 0, 0);
      }
    }
    const float inv128 = 1.f / 128.f;
#pragma unroll
    for (int nt = 0; nt < 8; ++nt)
#pragma unroll
      for (int r = 0; r < 4; ++r) {
        int row = m0 + l4 * 4 + r, col = nt * 16 + l15;
        float c = acc[nt][r] - fS[row] * fS[col] * inv128;
        acc[nt][r] = c;
        if (row == col) fS[128 + row] = c;
      }
    __syncthreads();
    if (tid < 128) {
      float d = fS[128 + tid];
      fS[256 + tid] = d > 0.f ? 1.f / sqrtf(d) : 0.f;
    }
    __syncthreads();
#pragma unroll
    for (int nt = 0; nt < 8; ++nt)
#pragma unroll
      for (int r = 0; r < 4; ++r) {
        int row = m0 + l4 * 4 + r, col = nt * 16 + l15;
        float di = fS[256 + row], dj = fS[256 + col];
        float v = acc[nt][r] * di * dj;
        v = fminf(1.f, fmaxf(-1.f, v));
        v = 0.5f * v + 0.5f;
        if (di == 0.f || dj == 0.f) v = 0.f;  // nan_to_num
        sAdj[row * 128 + SWZ(col, row)] = f2b(v);
      }
  }
  __syncthreads();

  // ---- op1: h1 = leaky(adj @ XW1b + b1) -> sBufA [128][256] ----
  {
    const unsigned short* XWb = XW1T + (size_t)b * 256 * 128;
    f32x4 acc[16] = {};
    const int m0 = w * 16;
#pragma unroll
    for (int ks = 0; ks < 4; ++ks) {
      int ar = m0 + l15;
      bf16x8 af = *(const bf16x8*)&sAdj[ar * 128 + SWZ(ks * 32 + l4 * 8, ar)];
#pragma unroll
      for (int nt = 0; nt < 16; ++nt) {
        bf16x8 bf = *(const bf16x8*)&XWb[(size_t)(nt * 16 + l15) * 128 + ks * 32 + l4 * 8];
        acc[nt] = __builtin_amdgcn_mfma_f32_16x16x32_bf16(af, bf, acc[nt], 0, 0, 0);
      }
    }
#pragma unroll
    for (int nt = 0; nt < 16; ++nt) {
      float bias = b1g[nt * 16 + l15];
#pragma unroll
      for (int r = 0; r < 4; ++r) {
        int row = m0 + l4 * 4 + r, col = nt * 16 + l15;
        sBufA[row * 256 + SWZ(col, row)] = f2b(leaky(acc[nt][r] + bias));
      }
    }
  }
  __syncthreads();

  // ---- op2: u2T = W2T @ h1^T -> sBufB [256][128] ----
  {
    f32x4 acc[2][8] = {};
    const int m0 = w * 32;
#pragma unroll
    for (int ks = 0; ks < 8; ++ks) {
      bf16x8 af[2];
#pragma unroll
      for (int mt = 0; mt < 2; ++mt)
        af[mt] = *(const bf16x8*)&W2T[(size_t)(m0 + mt * 16 + l15) * 256 + ks * 32 + l4 * 8];
#pragma unroll
      for (int nt = 0; nt < 8; ++nt) {
        int br = nt * 16 + l15;
        bf16x8 bf = *(const bf16x8*)&sBufA[br * 256 + SWZ(ks * 32 + l4 * 8, br)];
#pragma unroll
        for (int mt = 0; mt < 2; ++mt)
          acc[mt][nt] = __builtin_amdgcn_mfma_f32_16x16x32_bf16(af[mt], bf, acc[mt][nt], 0, 0, 0);
      }
    }
#pragma unroll
    for (int mt = 0; mt < 2; ++mt)
#pragma unroll
      for (int nt = 0; nt < 8; ++nt)
#pragma unroll
        for (int r = 0; r < 4; ++r) {
          int row = m0 + mt * 16 + l4 * 4 + r, col = nt * 16 + l15;
          sBufB[row * 128 + SWZ(col, row)] = f2b(acc[mt][nt][r]);
        }
  }
  __syncthreads();

  // ---- op3: h2 = leaky(adj @ u2 + b2) -> sBufA [128][256] ----
  {
    f32x4 acc[16] = {};
    const int m0 = w * 16;
#pragma unroll
    for (int ks = 0; ks < 4; ++ks) {
      int ar = m0 + l15;
      bf16x8 af = *(const bf16x8*)&sAdj[ar * 128 + SWZ(ks * 32 + l4 * 8, ar)];
#pragma unroll
      for (int nt = 0; nt < 16; ++nt) {
        int br = nt * 16 + l15;
        bf16x8 bf = *(const bf16x8*)&sBufB[br * 128 + SWZ(ks * 32 + l4 * 8, br)];
        acc[nt] = __builtin_amdgcn_mfma_f32_16x16x32_bf16(af, bf, acc[nt], 0, 0, 0);
      }
    }
#pragma unroll
    for (int nt = 0; nt < 16; ++nt) {
      float bias = b2g[nt * 16 + l15];
#pragma unroll
      for (int r = 0; r < 4; ++r) {
        int row = m0 + l4 * 4 + r, col = nt * 16 + l15;
        sBufA[row * 256 + SWZ(col, row)] = f2b(leaky(acc[nt][r] + bias));
      }
    }
  }
  __syncthreads();

  // ---- op4: u3T = W3T @ h2^T -> sBufB [64][128] (first 16KB) ----
  {
    f32x4 acc[4] = {};
    const int mrow = (w >> 1) * 16;
    const int ntb = (w & 1) * 4;
#pragma unroll
    for (int ks = 0; ks < 8; ++ks) {
      bf16x8 af = *(const bf16x8*)&W3T[(size_t)(mrow + l15) * 256 + ks * 32 + l4 * 8];
#pragma unroll
      for (int nti = 0; nti < 4; ++nti) {
        int br = (ntb + nti) * 16 + l15;
        bf16x8 bf = *(const bf16x8*)&sBufA[br * 256 + SWZ(ks * 32 + l4 * 8, br)];
        acc[nti] = __builtin_amdgcn_mfma_f32_16x16x32_bf16(af, bf, acc[nti], 0, 0, 0);
      }
    }
#pragma unroll
    for (int nti = 0; nti < 4; ++nti)
#pragma unroll
      for (int r = 0; r < 4; ++r) {
        int row = mrow + l4 * 4 + r, col = (ntb + nti) * 16 + l15;
        sBufB[row * 128 + SWZ(col, row)] = f2b(acc[nti][r]);
      }
  }
  __syncthreads();

  // ---- op5: xa = leaky(adj @ u3 + b3) -> fp32 [128][64] at sBufB+8192; mean ----
  {
    float* xaf = reinterpret_cast<float*>(sBufB + 8192);
    f32x4 acc[4] = {};
    const int m0 = w * 16;
#pragma unroll
    for (int ks = 0; ks < 4; ++ks) {
      int ar = m0 + l15;
      bf16x8 af = *(const bf16x8*)&sAdj[ar * 128 + SWZ(ks * 32 + l4 * 8, ar)];
#pragma unroll
      for (int nt = 0; nt < 4; ++nt) {
        int br = nt * 16 + l15;
        bf16x8 bf = *(const bf16x8*)&sBufB[br * 128 + SWZ(ks * 32 + l4 * 8, br)];
        acc[nt] = __builtin_amdgcn_mfma_f32_16x16x32_bf16(af, bf, acc[nt], 0, 0, 0);
      }
    }
#pragma unroll
    for (int nt = 0; nt < 4; ++nt) {
      float bias = b3g[nt * 16 + l15];
#pragma unroll
      for (int r = 0; r < 4; ++r) {
        int row = m0 + l4 * 4 + r, col = nt * 16 + l15;
        xaf[row * 64 + col] = leaky(acc[nt][r] + bias);
      }
    }
  }
  __syncthreads();
  if (tid < 64) {
    const float* xaf = reinterpret_cast<const float*>(sBufB + 8192);
    float s = 0.f;
    for (int i = 0; i < 128; ++i) s += xaf[i * 64 + tid];
    gXa[((size_t)b * 15 + a) * 64 + tid] = s * (1.f / 128.f);
  }
}

// ---------------- k_head: per-batch head ----------------
__global__ __launch_bounds__(256) void k_head(const float* __restrict__ gXa,
                                              const float* __restrict__ W4,
                                              const float* __restrict__ b4,
                                              float* __restrict__ out) {
  __shared__ float xb[15 * 64];
  __shared__ float c2[15 * 16];
  __shared__ float mu[15];
  __shared__ float dinv[15];
  __shared__ float yy[15 * 64];
  __shared__ float zz[15 * 64];
  const int b = blockIdx.x;
  const int tid = threadIdx.x;
  for (int e = tid; e < 960; e += 256) xb[e] = gXa[(size_t)b * 960 + e];
  __syncthreads();
  if (tid < 15) {
    float s = 0.f;
    for (int c = 0; c < 64; ++c) s += xb[tid * 64 + c];
    mu[tid] = s * (1.f / 64.f);
  }
  __syncthreads();
  if (tid < 225) {
    int p = tid / 15, q = tid % 15;
    float s = 0.f;
    for (int c = 0; c < 64; ++c)
      s += (xb[p * 64 + c] - mu[p]) * (xb[q * 64 + c] - mu[q]);
    c2[p * 16 + q] = s;
  }
  __syncthreads();
  if (tid < 15) {
    float d = c2[tid * 16 + tid];
    dinv[tid] = d > 0.f ? (1.f / sqrtf(d)) : 0.f;
  }
  __syncthreads();
  if (tid < 225) {
    int p = tid / 15, q = tid % 15;
    float v = c2[p * 16 + q] * dinv[p] * dinv[q];
    v = fminf(1.f, fmaxf(-1.f, v));
    if (dinv[p] == 0.f || dinv[q] == 0.f) v = 0.f;
    c2[p * 16 + q] = v;
  }
  __syncthreads();
  for (int e = tid; e < 960; e += 256) {
    int p = e >> 6, c = e & 63;
    float s = 0.f;
    for (int q = 0; q < 15; ++q) s += c2[p * 16 + q] * xb[q * 64 + c];
    yy[e] = s;
  }
  __syncthreads();
  for (int e = tid; e < 960; e += 256) {
    int p = e >> 6, c = e & 63;
    float s = b4[c];
    for (int k = 0; k < 64; ++k) s += yy[p * 64 + k] * W4[k * 64 + c];
    zz[e] = leaky(s);
  }
  __syncthreads();
  if (tid < 64) {
    float m = -INFINITY;
    for (int p = 0; p < 15; ++p) m = fmaxf(m, zz[p * 64 + tid]);
    out[(size_t)b * 64 + tid] = m;
  }
}

extern "C" void kernel_launch(void* const* d_in, const int* in_sizes, int n_in,
                              void* d_out, int out_size, void* d_ws, size_t ws_size,
                              hipStream_t stream) {
  const float* x  = (const float*)d_in[0];
  const float* W1 = (const float*)d_in[1];
  const float* b1 = (const float*)d_in[2];
  const float* W2 = (const float*)d_in[3];
  const float* b2 = (const float*)d_in[4];
  const float* W3 = (const float*)d_in[5];
  const float* b3 = (const float*)d_in[6];
  const float* W4 = (const float*)d_in[7];
  const float* b4 = (const float*)d_in[8];
  float* out = (float*)d_out;

  char* ws = (char*)d_ws;
  unsigned short* XW1T = (unsigned short*)ws;               // 32*256*128*2 = 2 MB
  unsigned short* W1T  = (unsigned short*)(ws + 2097152);   // 256*2048*2  = 1 MB
  unsigned short* W2T  = (unsigned short*)(ws + 3145728);   // 256*256*2   = 128 KB
  unsigned short* W3T  = (unsigned short*)(ws + 3276800);   // 64*256*2    = 32 KB
  float* gXa           = (float*)(ws + 3309568);            // 32*15*64*4  = 120 KB

  k_prep<<<148, 256, 0, stream>>>(W1, W2, W3, W1T, W2T, W3T);
  k_xw1<<<32, 512, 0, stream>>>(x, W1T, XW1T);
  k_chain<<<480, 512, 0, stream>>>(x, XW1T, W2T, W3T, b1, b2, b3, gXa);
  k_head<<<32, 256, 0, stream>>>(gXa, W4, b4, out);
}

// Round 4
// 148.708 us; speedup vs baseline: 3.9717x; 1.2422x over previous
//
#include <hip/hip_runtime.h>

// B=32, F=node=128, T=2048, HID=256, NC=64, A=15 windows
// adj held in registers per wave after syrk (A-frag rows == wave's C rows).
// LDS: two 32KB regions -> 66.5KB -> 2 blocks/CU.

typedef float f32x4 __attribute__((ext_vector_type(4)));
typedef __bf16 bf16x8 __attribute__((ext_vector_type(8)));
typedef unsigned short u16x8 __attribute__((ext_vector_type(8)));

__device__ inline unsigned short f2b(float f) {
  unsigned int u = __float_as_uint(f);
  unsigned int r = u + 0x7fffu + ((u >> 16) & 1u);
  return (unsigned short)(r >> 16);
}
__device__ inline float b2f(unsigned short u) {
  return __uint_as_float(((unsigned int)u) << 16);
}
__device__ inline float leaky(float v) { return v >= 0.f ? v : 0.2f * v; }

// XOR swizzle on element index (16B granularity), rows of 128 bf16 (256B)
#define SWZ(k, r) ((k) ^ (((r) & 7) << 3))

// ---------------- k_prep: transpose W1/W2/W3 to bf16 (row = out-feature) ----------------
__global__ __launch_bounds__(256) void k_prep(const float* __restrict__ W1,
                                              const float* __restrict__ W2,
                                              const float* __restrict__ W3,
                                              unsigned short* __restrict__ W1T,
                                              unsigned short* __restrict__ W2T,
                                              unsigned short* __restrict__ W3T) {
  __shared__ float t[64][65];
  const int bid = blockIdx.x;
  const float* src;
  unsigned short* dst;
  int K, N, k0, n0;
  if (bid < 128) {        // W1 [2048][256] -> W1T [256][2048]
    src = W1; dst = W1T; K = 2048; N = 256;
    k0 = (bid >> 2) * 64; n0 = (bid & 3) * 64;
  } else if (bid < 144) { // W2 [256][256] -> W2T [256][256]
    src = W2; dst = W2T; K = 256; N = 256;
    int i = bid - 128; k0 = (i >> 2) * 64; n0 = (i & 3) * 64;
  } else {                // W3 [256][64] -> W3T [64][256]
    src = W3; dst = W3T; K = 256; N = 64;
    int i = bid - 144; k0 = i * 64; n0 = 0;
  }
  const int tid = threadIdx.x;
#pragma unroll
  for (int it = 0; it < 16; ++it) {
    int e = tid + it * 256, r = e >> 6, c = e & 63;
    t[r][c] = src[(size_t)(k0 + r) * N + n0 + c];
  }
  __syncthreads();
#pragma unroll
  for (int it = 0; it < 16; ++it) {
    int e = tid + it * 256, rr = e >> 6, cc = e & 63;
    dst[(size_t)(n0 + rr) * K + k0 + cc] = f2b(t[cc][rr]);
  }
}

// ---------------- k_xw1: XW1T[b][hid][f] = (x_b @ W1)^T, 64 blocks, dbuf ----------------
__global__ __launch_bounds__(512) void k_xw1(const float* __restrict__ x,
                                             const unsigned short* __restrict__ W1T,
                                             unsigned short* __restrict__ XW1T) {
  __shared__ __align__(16) unsigned short sX[2][128 * 64];  // x tile [f][64k] bf16 swz
  const int tid = threadIdx.x;
  const int w = tid >> 6, lane = tid & 63;
  const int l15 = lane & 15, l4 = lane >> 4;
  const int hid0 = blockIdx.x * 128;    // 0 or 128
  const int b = blockIdx.y;
  const float* xb = x + (size_t)b * 128 * 2048;
  const int fr = tid >> 2, kc = (tid & 3) * 16;  // staging: row fr, 16 k-elems
  const int arow = hid0 + w * 16 + l15;          // W1T row for A-frags (per-wave unique)

  f32x4 xr[4];
  f32x4 acc[8] = {};  // m = w*16 slice, n = 128 f (8 nt)

  auto LOADX = [&](int kb) {
#pragma unroll
    for (int q = 0; q < 4; ++q)
      xr[q] = *(const f32x4*)&xb[(size_t)fr * 2048 + kb * 64 + kc + q * 4];
  };
  auto STOREX = [&](int buf) {
#pragma unroll
    for (int i = 0; i < 2; ++i) {
      u16x8 s;
#pragma unroll
      for (int j = 0; j < 8; ++j) s[j] = f2b(xr[i * 2 + (j >> 2)][j & 3]);
      *(u16x8*)&sX[buf][fr * 64 + SWZ(kc + i * 8, fr)] = s;
    }
  };

  LOADX(0);
  STOREX(0);
  __syncthreads();
  for (int kb = 0; kb < 32; ++kb) {
    if (kb < 31) LOADX(kb + 1);  // issue next tile loads; latency hidden by MFMA
    const int buf = kb & 1;
    bf16x8 af0 = *(const bf16x8*)&W1T[(size_t)arow * 2048 + kb * 64 + l4 * 8];
    bf16x8 af1 = *(const bf16x8*)&W1T[(size_t)arow * 2048 + kb * 64 + 32 + l4 * 8];
#pragma unroll
    for (int nt = 0; nt < 8; ++nt) {
      int br = nt * 16 + l15;
      bf16x8 b0 = *(const bf16x8*)&sX[buf][br * 64 + SWZ(l4 * 8, br)];
      acc[nt] = __builtin_amdgcn_mfma_f32_16x16x32_bf16(af0, b0, acc[nt], 0, 0, 0);
    }
#pragma unroll
    for (int nt = 0; nt < 8; ++nt) {
      int br = nt * 16 + l15;
      bf16x8 b1 = *(const bf16x8*)&sX[buf][br * 64 + SWZ(32 + l4 * 8, br)];
      acc[nt] = __builtin_amdgcn_mfma_f32_16x16x32_bf16(af1, b1, acc[nt], 0, 0, 0);
    }
    if (kb < 31) {
      STOREX(buf ^ 1);   // safe: buf^1 readers all passed previous barrier
      __syncthreads();
    }
  }
  unsigned short* dst = XW1T + (size_t)b * 256 * 128;
#pragma unroll
  for (int nt = 0; nt < 8; ++nt)
#pragma unroll
    for (int r = 0; r < 4; ++r) {
      int p = hid0 + w * 16 + l4 * 4 + r;
      int f = nt * 16 + l15;
      dst[p * 128 + f] = f2b(acc[nt][r]);
    }
}

// ---------------- k_chain: per-(b,a) fused MFMA chain, 66.5KB LDS ----------------
__global__ __launch_bounds__(512, 4) void k_chain(
    const float* __restrict__ x, const unsigned short* __restrict__ XW1T,
    const unsigned short* __restrict__ W2T, const unsigned short* __restrict__ W3T,
    const float* __restrict__ b1g, const float* __restrict__ b2g,
    const float* __restrict__ b3g, float* __restrict__ gXa) {
  __shared__ __align__(16) unsigned short R0[128 * 128];  // 32 KB
  __shared__ __align__(16) unsigned short R1[128 * 128];  // 32 KB
  __shared__ float fS[384];  // [0:128) sum, [128:256) diag, [256:384) dinv

  const int tid = threadIdx.x;
  const int w = tid >> 6, lane = tid & 63;
  const int l15 = lane & 15, l4 = lane >> 4;
  const int b = blockIdx.x / 15, a = blockIdx.x % 15;
  const int m0 = w * 16;

  // ---- phase 0: window -> win[j][f] bf16 swz in R0; row sums ----
  const float* xb = x + (size_t)b * 128 * 2048 + (size_t)a * 128;
#pragma unroll
  for (int it = 0; it < 8; ++it) {
    int e4 = tid + it * 512;
    int f = e4 >> 5;
    int j4 = (e4 & 31) << 2;
    f32x4 v = *(const f32x4*)&xb[(size_t)f * 2048 + j4];
#pragma unroll
    for (int q = 0; q < 4; ++q) {
      int r = j4 + q;
      R0[r * 128 + SWZ(f, r)] = f2b(v[q]);
    }
  }
  __syncthreads();
  if (tid < 128) {
    float s = 0.f;
    for (int t = 0; t < 128; ++t) s += b2f(R0[tid * 128 + t]);  // swz permutes within row
    fS[tid] = s;
  }
  __syncthreads();

  // ---- syrk: c = win @ win^T, center, scale -> adj bf16 in R1 ----
  {
    f32x4 acc8[8] = {};
#pragma unroll
    for (int ks = 0; ks < 4; ++ks) {
      int ar = m0 + l15;
      bf16x8 af = *(const bf16x8*)&R0[ar * 128 + SWZ(ks * 32 + l4 * 8, ar)];
#pragma unroll
      for (int nt = 0; nt < 8; ++nt) {
        int br = nt * 16 + l15;
        bf16x8 bf = *(const bf16x8*)&R0[br * 128 + SWZ(ks * 32 + l4 * 8, br)];
        acc8[nt] = __builtin_amdgcn_mfma_f32_16x16x32_bf16(af, bf, acc8[nt], 0, 0, 0);
      }
    }
    const float inv128 = 1.f / 128.f;
#pragma unroll
    for (int nt = 0; nt < 8; ++nt)
#pragma unroll
      for (int r = 0; r < 4; ++r) {
        int row = m0 + l4 * 4 + r, col = nt * 16 + l15;
        float c = acc8[nt][r] - fS[row] * fS[col] * inv128;
        acc8[nt][r] = c;
        if (row == col) fS[128 + row] = c;
      }
    __syncthreads();
    if (tid < 128) {
      float d = fS[128 + tid];
      fS[256 + tid] = d > 0.f ? 1.f / sqrtf(d) : 0.f;
    }
    __syncthreads();
#pragma unroll
    for (int nt = 0; nt < 8; ++nt)
#pragma unroll
      for (int r = 0; r < 4; ++r) {
        int row = m0 + l4 * 4 + r, col = nt * 16 + l15;
        float di = fS[256 + row], dj = fS[256 + col];
        float v = acc8[nt][r] * di * dj;
        v = fminf(1.f, fmaxf(-1.f, v));
        v = 0.5f * v + 0.5f;
        if (di == 0.f || dj == 0.f) v = 0.f;  // nan_to_num
        R1[row * 128 + SWZ(col, row)] = f2b(v);
      }
  }
  __syncthreads();  // B1

  // ---- adj A-fragments -> registers (wave w uses rows m0..m0+15 in ops 1,3,5) ----
  bf16x8 afj[4];
#pragma unroll
  for (int ks = 0; ks < 4; ++ks)
    afj[ks] = *(const bf16x8*)&R1[(m0 + l15) * 128 + SWZ(ks * 32 + l4 * 8, m0 + l15)];
  __syncthreads();  // B1b: all afj reads complete before R1 is overwritten

  // ---- op1: h1 = leaky(adj @ XW1b + b1); half0 -> R0, half1 -> R1 ----
  const unsigned short* XWb = XW1T + (size_t)b * 256 * 128;
#pragma unroll 1
  for (int half = 0; half < 2; ++half) {
    f32x4 acc[8] = {};
#pragma unroll
    for (int ks = 0; ks < 4; ++ks)
#pragma unroll
      for (int nt = 0; nt < 8; ++nt) {
        bf16x8 bf = *(const bf16x8*)&XWb[(size_t)(half * 128 + nt * 16 + l15) * 128 + ks * 32 + l4 * 8];
        acc[nt] = __builtin_amdgcn_mfma_f32_16x16x32_bf16(afj[ks], bf, acc[nt], 0, 0, 0);
      }
    unsigned short* Rd = half ? R1 : R0;
#pragma unroll
    for (int nt = 0; nt < 8; ++nt) {
      float bias = b1g[half * 128 + nt * 16 + l15];
#pragma unroll
      for (int r = 0; r < 4; ++r) {
        int row = m0 + l4 * 4 + r, col = nt * 16 + l15;
        Rd[row * 128 + SWZ(col, row)] = f2b(leaky(acc[nt][r] + bias));
      }
    }
  }
  __syncthreads();  // B2

  // ---- op2: u2T = W2T @ h1^T (k over hid 256: R0 then R1), acc in regs ----
  {
    f32x4 u2[2][8] = {};
#pragma unroll
    for (int ks = 0; ks < 8; ++ks) {
      bf16x8 a0 = *(const bf16x8*)&W2T[(size_t)(w * 32 + l15) * 256 + ks * 32 + l4 * 8];
      bf16x8 a1 = *(const bf16x8*)&W2T[(size_t)(w * 32 + 16 + l15) * 256 + ks * 32 + l4 * 8];
      const unsigned short* Rs = (ks < 4) ? R0 : R1;
      int kk = (ks & 3) * 32 + l4 * 8;
#pragma unroll
      for (int nt = 0; nt < 8; ++nt) {
        int br = nt * 16 + l15;
        bf16x8 bf = *(const bf16x8*)&Rs[br * 128 + SWZ(kk, br)];
        u2[0][nt] = __builtin_amdgcn_mfma_f32_16x16x32_bf16(a0, bf, u2[0][nt], 0, 0, 0);
        u2[1][nt] = __builtin_amdgcn_mfma_f32_16x16x32_bf16(a1, bf, u2[1][nt], 0, 0, 0);
      }
    }
    __syncthreads();  // B3: all h1 reads done
#pragma unroll
    for (int mt = 0; mt < 2; ++mt)
#pragma unroll
      for (int nt = 0; nt < 8; ++nt)
#pragma unroll
        for (int r = 0; r < 4; ++r) {
          int grow = w * 32 + mt * 16 + l4 * 4 + r;  // hid 0..255
          int col = nt * 16 + l15;
          unsigned short* Rd = (grow < 128) ? R0 : R1;
          int lr = grow & 127;
          Rd[lr * 128 + SWZ(col, lr)] = f2b(u2[mt][nt][r]);
        }
  }
  __syncthreads();  // B4

  // ---- op3h0: h2[:,0:128] = leaky(adj @ u2[:,0:128] + b2) (reads R0) ----
  f32x4 h2acc[8];
#pragma unroll
  for (int nt = 0; nt < 8; ++nt) h2acc[nt] = f32x4{0.f, 0.f, 0.f, 0.f};
#pragma unroll
  for (int ks = 0; ks < 4; ++ks)
#pragma unroll
    for (int nt = 0; nt < 8; ++nt) {
      int br = nt * 16 + l15;
      bf16x8 bf = *(const bf16x8*)&R0[br * 128 + SWZ(ks * 32 + l4 * 8, br)];
      h2acc[nt] = __builtin_amdgcn_mfma_f32_16x16x32_bf16(afj[ks], bf, h2acc[nt], 0, 0, 0);
    }
  __syncthreads();  // B5
#pragma unroll
  for (int nt = 0; nt < 8; ++nt) {
    float bias = b2g[nt * 16 + l15];
#pragma unroll
    for (int r = 0; r < 4; ++r) {
      int row = m0 + l4 * 4 + r, col = nt * 16 + l15;
      R0[row * 128 + SWZ(col, row)] = f2b(leaky(h2acc[nt][r] + bias));
    }
  }
  __syncthreads();  // B6

  // ---- op4p0: u3T += W3T[:,0:128] @ h2h0^T (reads R0) ----
  f32x4 u3[4] = {};
  const int mrow = (w >> 1) * 16, ntb = (w & 1) * 4;
#pragma unroll
  for (int ks = 0; ks < 4; ++ks) {
    bf16x8 a3 = *(const bf16x8*)&W3T[(size_t)(mrow + l15) * 256 + ks * 32 + l4 * 8];
#pragma unroll
    for (int nti = 0; nti < 4; ++nti) {
      int br = (ntb + nti) * 16 + l15;
      bf16x8 bf = *(const bf16x8*)&R0[br * 128 + SWZ(ks * 32 + l4 * 8, br)];
      u3[nti] = __builtin_amdgcn_mfma_f32_16x16x32_bf16(a3, bf, u3[nti], 0, 0, 0);
    }
  }

  // ---- op3h1: h2[:,128:256] (reads R1) ----
#pragma unroll
  for (int nt = 0; nt < 8; ++nt) h2acc[nt] = f32x4{0.f, 0.f, 0.f, 0.f};
#pragma unroll
  for (int ks = 0; ks < 4; ++ks)
#pragma unroll
    for (int nt = 0; nt < 8; ++nt) {
      int br = nt * 16 + l15;
      bf16x8 bf = *(const bf16x8*)&R1[br * 128 + SWZ(ks * 32 + l4 * 8, br)];
      h2acc[nt] = __builtin_amdgcn_mfma_f32_16x16x32_bf16(afj[ks], bf, h2acc[nt], 0, 0, 0);
    }
  __syncthreads();  // B7
#pragma unroll
  for (int nt = 0; nt < 8; ++nt) {
    float bias = b2g[128 + nt * 16 + l15];
#pragma unroll
    for (int r = 0; r < 4; ++r) {
      int row = m0 + l4 * 4 + r, col = nt * 16 + l15;
      R1[row * 128 + SWZ(col, row)] = f2b(leaky(h2acc[nt][r] + bias));
    }
  }
  __syncthreads();  // B8

  // ---- op4p1: u3T += W3T[:,128:256] @ h2h1^T (reads R1) ----
#pragma unroll
  for (int ks = 0; ks < 4; ++ks) {
    bf16x8 a3 = *(const bf16x8*)&W3T[(size_t)(mrow + l15) * 256 + 128 + ks * 32 + l4 * 8];
#pragma unroll
    for (int nti = 0; nti < 4; ++nti) {
      int br = (ntb + nti) * 16 + l15;
      bf16x8 bf = *(const bf16x8*)&R1[br * 128 + SWZ(ks * 32 + l4 * 8, br)];
      u3[nti] = __builtin_amdgcn_mfma_f32_16x16x32_bf16(a3, bf, u3[nti], 0, 0, 0);
    }
  }
  __syncthreads();  // B9: h2h0 readers (op4p0) long done; gate u3T write vs op4p1 reads ordering
  // ---- write u3T -> R0 rows 0..63 ----
#pragma unroll
  for (int nti = 0; nti < 4; ++nti)
#pragma unroll
    for (int r = 0; r < 4; ++r) {
      int grow = mrow + l4 * 4 + r;           // 0..63
      int col = (ntb + nti) * 16 + l15;       // 0..127
      R0[grow * 128 + SWZ(col, grow)] = f2b(u3[nti][r]);
    }
  __syncthreads();  // B10

  // ---- op5: xa = leaky(adj @ u3 + b3) -> fp32 [128][64] in R1; mean ----
  {
    f32x4 xacc[4] = {};
#pragma unroll
    for (int ks = 0; ks < 4; ++ks)
#pragma unroll
      for (int nt = 0; nt < 4; ++nt) {
        int br = nt * 16 + l15;
        bf16x8 bf = *(const bf16x8*)&R0[br * 128 + SWZ(ks * 32 + l4 * 8, br)];
        xacc[nt] = __builtin_amdgcn_mfma_f32_16x16x32_bf16(afj[ks], bf, xacc[nt], 0, 0, 0);
      }
    float* xaf = reinterpret_cast<float*>(R1);
#pragma unroll
    for (int nt = 0; nt < 4; ++nt) {
      float bias = b3g[nt * 16 + l15];
#pragma unroll
      for (int r = 0; r < 4; ++r) {
        int row = m0 + l4 * 4 + r, col = nt * 16 + l15;
        xaf[row * 64 + col] = leaky(xacc[nt][r] + bias);
      }
    }
  }
  __syncthreads();  // B11
  if (tid < 64) {
    const float* xaf = reinterpret_cast<const float*>(R1);
    float s = 0.f;
    for (int i = 0; i < 128; ++i) s += xaf[i * 64 + tid];
    gXa[((size_t)b * 15 + a) * 64 + tid] = s * (1.f / 128.f);
  }
}

// ---------------- k_head: per-batch head ----------------
__global__ __launch_bounds__(256) void k_head(const float* __restrict__ gXa,
                                              const float* __restrict__ W4,
                                              const float* __restrict__ b4,
                                              float* __restrict__ out) {
  __shared__ float xb[15 * 64];
  __shared__ float c2[15 * 16];
  __shared__ float mu[15];
  __shared__ float dinv[15];
  __shared__ float yy[15 * 64];
  __shared__ float zz[15 * 64];
  const int b = blockIdx.x;
  const int tid = threadIdx.x;
  for (int e = tid; e < 960; e += 256) xb[e] = gXa[(size_t)b * 960 + e];
  __syncthreads();
  if (tid < 15) {
    float s = 0.f;
    for (int c = 0; c < 64; ++c) s += xb[tid * 64 + c];
    mu[tid] = s * (1.f / 64.f);
  }
  __syncthreads();
  if (tid < 225) {
    int p = tid / 15, q = tid % 15;
    float s = 0.f;
    for (int c = 0; c < 64; ++c)
      s += (xb[p * 64 + c] - mu[p]) * (xb[q * 64 + c] - mu[q]);
    c2[p * 16 + q] = s;
  }
  __syncthreads();
  if (tid < 15) {
    float d = c2[tid * 16 + tid];
    dinv[tid] = d > 0.f ? (1.f / sqrtf(d)) : 0.f;
  }
  __syncthreads();
  if (tid < 225) {
    int p = tid / 15, q = tid % 15;
    float v = c2[p * 16 + q] * dinv[p] * dinv[q];
    v = fminf(1.f, fmaxf(-1.f, v));
    if (dinv[p] == 0.f || dinv[q] == 0.f) v = 0.f;
    c2[p * 16 + q] = v;
  }
  __syncthreads();
  for (int e = tid; e < 960; e += 256) {
    int p = e >> 6, c = e & 63;
    float s = 0.f;
    for (int q = 0; q < 15; ++q) s += c2[p * 16 + q] * xb[q * 64 + c];
    yy[e] = s;
  }
  __syncthreads();
  for (int e = tid; e < 960; e += 256) {
    int p = e >> 6, c = e & 63;
    float s = b4[c];
    for (int k = 0; k < 64; ++k) s += yy[p * 64 + k] * W4[k * 64 + c];
    zz[e] = leaky(s);
  }
  __syncthreads();
  if (tid < 64) {
    float m = -INFINITY;
    for (int p = 0; p < 15; ++p) m = fmaxf(m, zz[p * 64 + tid]);
    out[(size_t)b * 64 + tid] = m;
  }
}

extern "C" void kernel_launch(void* const* d_in, const int* in_sizes, int n_in,
                              void* d_out, int out_size, void* d_ws, size_t ws_size,
                              hipStream_t stream) {
  const float* x  = (const float*)d_in[0];
  const float* W1 = (const float*)d_in[1];
  const float* b1 = (const float*)d_in[2];
  const float* W2 = (const float*)d_in[3];
  const float* b2 = (const float*)d_in[4];
  const float* W3 = (const float*)d_in[5];
  const float* b3 = (const float*)d_in[6];
  const float* W4 = (const float*)d_in[7];
  const float* b4 = (const float*)d_in[8];
  float* out = (float*)d_out;

  char* ws = (char*)d_ws;
  unsigned short* XW1T = (unsigned short*)ws;               // 32*256*128*2 = 2 MB
  unsigned short* W1T  = (unsigned short*)(ws + 2097152);   // 256*2048*2  = 1 MB
  unsigned short* W2T  = (unsigned short*)(ws + 3145728);   // 256*256*2   = 128 KB
  unsigned short* W3T  = (unsigned short*)(ws + 3276800);   // 64*256*2    = 32 KB
  float* gXa           = (float*)(ws + 3309568);            // 32*15*64*4  = 120 KB

  k_prep<<<148, 256, 0, stream>>>(W1, W2, W3, W1T, W2T, W3T);
  dim3 gx(2, 32);
  k_xw1<<<gx, 512, 0, stream>>>(x, W1T, XW1T);
  k_chain<<<480, 512, 0, stream>>>(x, XW1T, W2T, W3T, b1, b2, b3, gXa);
  k_head<<<32, 256, 0, stream>>>(gXa, W4, b4, out);
}

// Round 5
// 132.849 us; speedup vs baseline: 4.4458x; 1.1194x over previous
//
#include <hip/hip_runtime.h>

// B=32, F=node=128, T=2048, HID=256, NC=64, A=15 windows
// xT[b][t][f] precomputed (bf16). k_chain: win load coalesced; sums via MFMA;
// adj intra-wave; 67KB LDS -> 2 blocks/CU.

typedef float f32x4 __attribute__((ext_vector_type(4)));
typedef __bf16 bf16x8 __attribute__((ext_vector_type(8)));
typedef unsigned short u16x4 __attribute__((ext_vector_type(4)));
typedef unsigned short u16x8 __attribute__((ext_vector_type(8)));

__device__ inline unsigned short f2b(float f) {
  unsigned int u = __float_as_uint(f);
  unsigned int r = u + 0x7fffu + ((u >> 16) & 1u);
  return (unsigned short)(r >> 16);
}
__device__ inline float leaky(float v) { return v >= 0.f ? v : 0.2f * v; }

#define SWZ(k, r) ((k) ^ (((r) & 7) << 3))

// ---------------- k_prep: W transposes (bid<148) + x transpose to xT (bid>=148) ----
__global__ __launch_bounds__(256) void k_prep(const float* __restrict__ x,
                                              const float* __restrict__ W1,
                                              const float* __restrict__ W2,
                                              const float* __restrict__ W3,
                                              unsigned short* __restrict__ W1T,
                                              unsigned short* __restrict__ W2T,
                                              unsigned short* __restrict__ W3T,
                                              unsigned short* __restrict__ xT) {
  __shared__ float t[64][65];
  const int bid = blockIdx.x;
  const int tid = threadIdx.x;
  if (bid < 148) {
    const float* src;
    unsigned short* dst;
    int K, N, k0, n0;
    if (bid < 128) {        // W1 [2048][256] -> W1T [256][2048]
      src = W1; dst = W1T; K = 2048; N = 256;
      k0 = (bid >> 2) * 64; n0 = (bid & 3) * 64;
    } else if (bid < 144) { // W2 [256][256] -> W2T [256][256]
      src = W2; dst = W2T; K = 256; N = 256;
      int i = bid - 128; k0 = (i >> 2) * 64; n0 = (i & 3) * 64;
    } else {                // W3 [256][64] -> W3T [64][256]
      src = W3; dst = W3T; K = 256; N = 64;
      int i = bid - 144; k0 = i * 64; n0 = 0;
    }
#pragma unroll
    for (int it = 0; it < 16; ++it) {
      int e = tid + it * 256, r = e >> 6, c = e & 63;
      t[r][c] = src[(size_t)(k0 + r) * N + n0 + c];
    }
    __syncthreads();
#pragma unroll
    for (int it = 0; it < 16; ++it) {
      int e = tid + it * 256, rr = e >> 6, cc = e & 63;
      dst[(size_t)(n0 + rr) * K + k0 + cc] = f2b(t[cc][rr]);
    }
  } else {
    // x [32][128][2048] fp32 -> xT [32][2048][128] bf16, 64x64 tiles
    int idx = bid - 148;               // 0..2047
    int b = idx >> 6, rem = idx & 63;
    int tt = rem >> 1, ft = rem & 1;
    int t0 = tt * 64, f0 = ft * 64;
    const float* xb = x + ((size_t)b * 128 + f0) * 2048 + t0;
#pragma unroll
    for (int it = 0; it < 16; ++it) {
      int e = tid + it * 256, r = e >> 6, c = e & 63;   // r=f-rel, c=t-rel
      t[r][c] = xb[(size_t)r * 2048 + c];
    }
    __syncthreads();
    unsigned short* dst = xT + ((size_t)b * 2048 + t0) * 128 + f0;
#pragma unroll
    for (int it = 0; it < 4; ++it) {
      int e = tid + it * 256, rr = e >> 4, c4 = (e & 15) * 4;  // rr=t-rel, c4=f-rel
      u16x4 s;
#pragma unroll
      for (int q = 0; q < 4; ++q) s[q] = f2b(t[c4 + q][rr]);
      *(u16x4*)&dst[rr * 128 + c4] = s;
    }
  }
}

// ---------------- k_xw1: XW1T[b][hid][f] = (x_b @ W1)^T, 256 blocks ----------------
__global__ __launch_bounds__(512) void k_xw1(const float* __restrict__ x,
                                             const unsigned short* __restrict__ W1T,
                                             unsigned short* __restrict__ XW1T) {
  __shared__ __align__(16) unsigned short sX[2][64 * 64];  // [f][k] bf16 swz, 8KB each
  const int tid = threadIdx.x;
  const int w = tid >> 6, lane = tid & 63;
  const int l15 = lane & 15, l4 = lane >> 4;
  const int bx = blockIdx.x;
  const int hid0 = (bx >> 1) * 64, f0 = (bx & 1) * 64;
  const int b = blockIdx.y;
  const float* xb = x + ((size_t)b * 128 + f0) * 2048;
  const int arow = hid0 + (w & 3) * 16 + l15;   // W1T row for this wave's m-tile
  const int nb = (w >> 2) * 32;                 // f-offset for this wave's 2 n-tiles
  const int fr = tid >> 3, k8 = (tid & 7) * 8;  // staging map

  f32x4 xr2[2];
  f32x4 acc[2] = {};

  auto LOADX = [&](int kb) {
    xr2[0] = *(const f32x4*)&xb[(size_t)fr * 2048 + kb * 64 + k8];
    xr2[1] = *(const f32x4*)&xb[(size_t)fr * 2048 + kb * 64 + k8 + 4];
  };
  auto STOREX = [&](int buf) {
    u16x8 s;
#pragma unroll
    for (int j = 0; j < 8; ++j) s[j] = f2b(xr2[j >> 2][j & 3]);
    *(u16x8*)&sX[buf][fr * 64 + SWZ(k8, fr)] = s;
  };

  LOADX(0);
  STOREX(0);
  __syncthreads();
  for (int kb = 0; kb < 32; ++kb) {
    if (kb < 31) LOADX(kb + 1);
    const int buf = kb & 1;
    bf16x8 af0 = *(const bf16x8*)&W1T[(size_t)arow * 2048 + kb * 64 + l4 * 8];
    bf16x8 af1 = *(const bf16x8*)&W1T[(size_t)arow * 2048 + kb * 64 + 32 + l4 * 8];
#pragma unroll
    for (int nt = 0; nt < 2; ++nt) {
      int br = nb + nt * 16 + l15;
      bf16x8 b0 = *(const bf16x8*)&sX[buf][br * 64 + SWZ(l4 * 8, br)];
      acc[nt] = __builtin_amdgcn_mfma_f32_16x16x32_bf16(af0, b0, acc[nt], 0, 0, 0);
    }
#pragma unroll
    for (int nt = 0; nt < 2; ++nt) {
      int br = nb + nt * 16 + l15;
      bf16x8 b1 = *(const bf16x8*)&sX[buf][br * 64 + SWZ(32 + l4 * 8, br)];
      acc[nt] = __builtin_amdgcn_mfma_f32_16x16x32_bf16(af1, b1, acc[nt], 0, 0, 0);
    }
    if (kb < 31) {
      STOREX(buf ^ 1);
      __syncthreads();
    }
  }
  unsigned short* dst = XW1T + (size_t)b * 256 * 128;
#pragma unroll
  for (int nt = 0; nt < 2; ++nt)
#pragma unroll
    for (int r = 0; r < 4; ++r) {
      int p = hid0 + (w & 3) * 16 + l4 * 4 + r;
      int f = f0 + nb + nt * 16 + l15;
      dst[p * 128 + f] = f2b(acc[nt][r]);
    }
}

// ---------------- k_chain: per-(b,a) fused MFMA chain ----------------
__global__ __launch_bounds__(512, 4) void k_chain(
    const unsigned short* __restrict__ xT, const unsigned short* __restrict__ XW1T,
    const unsigned short* __restrict__ W2T, const unsigned short* __restrict__ W3T,
    const float* __restrict__ b1g, const float* __restrict__ b2g,
    const float* __restrict__ b3g, float* __restrict__ gXa) {
  __shared__ __align__(16) unsigned short R0[128 * 128];  // 32 KB: adj -> h1a -> u2a/h2h0 -> u3 -> part
  __shared__ __align__(16) unsigned short R1[128 * 128];  // 32 KB: win -> h1b -> u2b/h2h1 -> xa
  __shared__ float fS[384];  // [0:128) sum, [128:256) diag, [256:384) dinv

  const int tid = threadIdx.x;
  const int w = tid >> 6, lane = tid & 63;
  const int l15 = lane & 15, l4 = lane >> 4;
  const int b = blockIdx.x / 15, a = blockIdx.x % 15;
  const int m0 = w * 16;

  // ---- P0: load win[j=node][f] from xT (coalesced bf16) ----
  const unsigned short* src = xT + ((size_t)b * 2048 + (size_t)a * 128) * 128;
#pragma unroll
  for (int it = 0; it < 4; ++it) {
    int tt = tid + it * 512;
    int j = tt >> 4, f8 = (tt & 15) * 8;
    *(u16x8*)&R1[j * 128 + SWZ(f8, j)] = *(const u16x8*)&src[j * 128 + f8];
  }
  __syncthreads();

  // ---- P1: sums (MFMA ones) + syrk; center+scale -> adj in R0 ----
  {
    f32x4 acc8[8] = {};
    f32x4 sacc = {};
    bf16x8 ones;
#pragma unroll
    for (int q = 0; q < 8; ++q) ones[q] = (__bf16)1.0f;
    __builtin_amdgcn_s_setprio(1);
#pragma unroll
    for (int ks = 0; ks < 4; ++ks) {
      int ar = m0 + l15;
      bf16x8 af = *(const bf16x8*)&R1[ar * 128 + SWZ(ks * 32 + l4 * 8, ar)];
      sacc = __builtin_amdgcn_mfma_f32_16x16x32_bf16(af, ones, sacc, 0, 0, 0);
#pragma unroll
      for (int nt = 0; nt < 8; ++nt) {
        int br = nt * 16 + l15;
        bf16x8 bf = *(const bf16x8*)&R1[br * 128 + SWZ(ks * 32 + l4 * 8, br)];
        acc8[nt] = __builtin_amdgcn_mfma_f32_16x16x32_bf16(af, bf, acc8[nt], 0, 0, 0);
      }
    }
    __builtin_amdgcn_s_setprio(0);
    if (l15 == 0) {
#pragma unroll
      for (int r = 0; r < 4; ++r) fS[m0 + l4 * 4 + r] = sacc[r];
    }
    __syncthreads();
    const float inv128 = 1.f / 128.f;
    float fcol[8];
#pragma unroll
    for (int nt = 0; nt < 8; ++nt) fcol[nt] = fS[nt * 16 + l15];
#pragma unroll
    for (int nt = 0; nt < 8; ++nt)
#pragma unroll
      for (int r = 0; r < 4; ++r) {
        int row = m0 + l4 * 4 + r, col = nt * 16 + l15;
        float c = acc8[nt][r] - sacc[r] * fcol[nt] * inv128;
        acc8[nt][r] = c;
        if (row == col) fS[128 + row] = c;
      }
    __syncthreads();
    if (tid < 128) {
      float d = fS[128 + tid];
      fS[256 + tid] = d > 0.f ? 1.f / sqrtf(d) : 0.f;
    }
    __syncthreads();
    float djv[8], div[4];
#pragma unroll
    for (int nt = 0; nt < 8; ++nt) djv[nt] = fS[256 + nt * 16 + l15];
#pragma unroll
    for (int r = 0; r < 4; ++r) div[r] = fS[256 + m0 + l4 * 4 + r];
#pragma unroll
    for (int nt = 0; nt < 8; ++nt)
#pragma unroll
      for (int r = 0; r < 4; ++r) {
        int row = m0 + l4 * 4 + r, col = nt * 16 + l15;
        float v = acc8[nt][r] * div[r] * djv[nt];
        v = fminf(1.f, fmaxf(-1.f, v));
        v = 0.5f * v + 0.5f;
        if (div[r] == 0.f || djv[nt] == 0.f) v = 0.f;  // nan_to_num
        R0[row * 128 + SWZ(col, row)] = f2b(v);
      }
  }
  // adj rows m0..m0+15 written and re-read by the SAME wave -> no barrier needed
  bf16x8 afj[4];
#pragma unroll
  for (int ks = 0; ks < 4; ++ks)
    afj[ks] = *(const bf16x8*)&R0[(m0 + l15) * 128 + SWZ(ks * 32 + l4 * 8, m0 + l15)];
  __syncthreads();  // B1b: afj reads done before h1half0 overwrites R0

  // ---- op1: h1 = leaky(adj @ XW1b + b1); half0 -> R0, half1 -> R1 ----
  const unsigned short* XWb = XW1T + (size_t)b * 256 * 128;
#pragma unroll 1
  for (int half = 0; half < 2; ++half) {
    f32x4 acc[8] = {};
    __builtin_amdgcn_s_setprio(1);
#pragma unroll
    for (int ks = 0; ks < 4; ++ks)
#pragma unroll
      for (int nt = 0; nt < 8; ++nt) {
        bf16x8 bf = *(const bf16x8*)&XWb[(size_t)(half * 128 + nt * 16 + l15) * 128 + ks * 32 + l4 * 8];
        acc[nt] = __builtin_amdgcn_mfma_f32_16x16x32_bf16(afj[ks], bf, acc[nt], 0, 0, 0);
      }
    __builtin_amdgcn_s_setprio(0);
    unsigned short* Rd = half ? R1 : R0;
#pragma unroll
    for (int nt = 0; nt < 8; ++nt) {
      float bias = b1g[half * 128 + nt * 16 + l15];
#pragma unroll
      for (int r = 0; r < 4; ++r) {
        int row = m0 + l4 * 4 + r, col = nt * 16 + l15;
        Rd[row * 128 + SWZ(col, row)] = f2b(leaky(acc[nt][r] + bias));
      }
    }
  }
  __syncthreads();  // B2

  // ---- op2: u2T = W2T @ h1^T (k over hid 256: R0 then R1) ----
  {
    f32x4 u2[2][8] = {};
    __builtin_amdgcn_s_setprio(1);
#pragma unroll
    for (int ks = 0; ks < 8; ++ks) {
      bf16x8 a0 = *(const bf16x8*)&W2T[(size_t)(w * 32 + l15) * 256 + ks * 32 + l4 * 8];
      bf16x8 a1 = *(const bf16x8*)&W2T[(size_t)(w * 32 + 16 + l15) * 256 + ks * 32 + l4 * 8];
      const unsigned short* Rs = (ks < 4) ? R0 : R1;
      int kk = (ks & 3) * 32 + l4 * 8;
#pragma unroll
      for (int nt = 0; nt < 8; ++nt) {
        int br = nt * 16 + l15;
        bf16x8 bf = *(const bf16x8*)&Rs[br * 128 + SWZ(kk, br)];
        u2[0][nt] = __builtin_amdgcn_mfma_f32_16x16x32_bf16(a0, bf, u2[0][nt], 0, 0, 0);
        u2[1][nt] = __builtin_amdgcn_mfma_f32_16x16x32_bf16(a1, bf, u2[1][nt], 0, 0, 0);
      }
    }
    __builtin_amdgcn_s_setprio(0);
    __syncthreads();  // B3: all h1 reads done
#pragma unroll
    for (int mt = 0; mt < 2; ++mt)
#pragma unroll
      for (int nt = 0; nt < 8; ++nt)
#pragma unroll
        for (int r = 0; r < 4; ++r) {
          int grow = w * 32 + mt * 16 + l4 * 4 + r;  // hid 0..255
          int col = nt * 16 + l15;
          unsigned short* Rd = (grow < 128) ? R0 : R1;
          int lr = grow & 127;
          Rd[lr * 128 + SWZ(col, lr)] = f2b(u2[mt][nt][r]);
        }
  }
  __syncthreads();  // B4

  // ---- op3h0: h2[:,0:128] = leaky(adj @ u2a + b2) (reads R0) ----
  f32x4 h2acc[8];
#pragma unroll
  for (int nt = 0; nt < 8; ++nt) h2acc[nt] = f32x4{0.f, 0.f, 0.f, 0.f};
  __builtin_amdgcn_s_setprio(1);
#pragma unroll
  for (int ks = 0; ks < 4; ++ks)
#pragma unroll
    for (int nt = 0; nt < 8; ++nt) {
      int br = nt * 16 + l15;
      bf16x8 bf = *(const bf16x8*)&R0[br * 128 + SWZ(ks * 32 + l4 * 8, br)];
      h2acc[nt] = __builtin_amdgcn_mfma_f32_16x16x32_bf16(afj[ks], bf, h2acc[nt], 0, 0, 0);
    }
  __builtin_amdgcn_s_setprio(0);
  __syncthreads();  // B5
#pragma unroll
  for (int nt = 0; nt < 8; ++nt) {
    float bias = b2g[nt * 16 + l15];
#pragma unroll
    for (int r = 0; r < 4; ++r) {
      int row = m0 + l4 * 4 + r, col = nt * 16 + l15;
      R0[row * 128 + SWZ(col, row)] = f2b(leaky(h2acc[nt][r] + bias));
    }
  }
  __syncthreads();  // B6

  // ---- op4p0: u3T += W3T[:,0:128] @ h2h0^T ;; op3h1 (reads R1) ----
  f32x4 u3[4] = {};
  const int mrow = (w >> 1) * 16, ntb = (w & 1) * 4;
  __builtin_amdgcn_s_setprio(1);
#pragma unroll
  for (int ks = 0; ks < 4; ++ks) {
    bf16x8 a3 = *(const bf16x8*)&W3T[(size_t)(mrow + l15) * 256 + ks * 32 + l4 * 8];
#pragma unroll
    for (int nti = 0; nti < 4; ++nti) {
      int br = (ntb + nti) * 16 + l15;
      bf16x8 bf = *(const bf16x8*)&R0[br * 128 + SWZ(ks * 32 + l4 * 8, br)];
      u3[nti] = __builtin_amdgcn_mfma_f32_16x16x32_bf16(a3, bf, u3[nti], 0, 0, 0);
    }
  }
#pragma unroll
  for (int nt = 0; nt < 8; ++nt) h2acc[nt] = f32x4{0.f, 0.f, 0.f, 0.f};
#pragma unroll
  for (int ks = 0; ks < 4; ++ks)
#pragma unroll
    for (int nt = 0; nt < 8; ++nt) {
      int br = nt * 16 + l15;
      bf16x8 bf = *(const bf16x8*)&R1[br * 128 + SWZ(ks * 32 + l4 * 8, br)];
      h2acc[nt] = __builtin_amdgcn_mfma_f32_16x16x32_bf16(afj[ks], bf, h2acc[nt], 0, 0, 0);
    }
  __builtin_amdgcn_s_setprio(0);
  __syncthreads();  // B7
#pragma unroll
  for (int nt = 0; nt < 8; ++nt) {
    float bias = b2g[128 + nt * 16 + l15];
#pragma unroll
    for (int r = 0; r < 4; ++r) {
      int row = m0 + l4 * 4 + r, col = nt * 16 + l15;
      R1[row * 128 + SWZ(col, row)] = f2b(leaky(h2acc[nt][r] + bias));
    }
  }
  __syncthreads();  // B8

  // ---- op4p1: u3T += W3T[:,128:256] @ h2h1^T (reads R1) ----
  __builtin_amdgcn_s_setprio(1);
#pragma unroll
  for (int ks = 0; ks < 4; ++ks) {
    bf16x8 a3 = *(const bf16x8*)&W3T[(size_t)(mrow + l15) * 256 + 128 + ks * 32 + l4 * 8];
#pragma unroll
    for (int nti = 0; nti < 4; ++nti) {
      int br = (ntb + nti) * 16 + l15;
      bf16x8 bf = *(const bf16x8*)&R1[br * 128 + SWZ(ks * 32 + l4 * 8, br)];
      u3[nti] = __builtin_amdgcn_mfma_f32_16x16x32_bf16(a3, bf, u3[nti], 0, 0, 0);
    }
  }
  __builtin_amdgcn_s_setprio(0);
  __syncthreads();  // B9
#pragma unroll
  for (int nti = 0; nti < 4; ++nti)
#pragma unroll
    for (int r = 0; r < 4; ++r) {
      int grow = mrow + l4 * 4 + r;           // 0..63 (class)
      int col = (ntb + nti) * 16 + l15;       // 0..127 (node)
      R0[grow * 128 + SWZ(col, grow)] = f2b(u3[nti][r]);
    }
  __syncthreads();  // B10

  // ---- op5: xa = leaky(adj @ u3 + b3) -> fp32 [128][64] in R1; parallel mean ----
  {
    f32x4 xacc[4] = {};
    __builtin_amdgcn_s_setprio(1);
#pragma unroll
    for (int ks = 0; ks < 4; ++ks)
#pragma unroll
      for (int nt = 0; nt < 4; ++nt) {
        int br = nt * 16 + l15;
        bf16x8 bf = *(const bf16x8*)&R0[br * 128 + SWZ(ks * 32 + l4 * 8, br)];
        xacc[nt] = __builtin_amdgcn_mfma_f32_16x16x32_bf16(afj[ks], bf, xacc[nt], 0, 0, 0);
      }
    __builtin_amdgcn_s_setprio(0);
    float* xaf = reinterpret_cast<float*>(R1);
#pragma unroll
    for (int nt = 0; nt < 4; ++nt) {
      float bias = b3g[nt * 16 + l15];
#pragma unroll
      for (int r = 0; r < 4; ++r) {
        int row = m0 + l4 * 4 + r, col = nt * 16 + l15;
        xaf[row * 64 + col] = leaky(xacc[nt][r] + bias);
      }
    }
  }
  __syncthreads();  // B11
  {
    const float* xaf = reinterpret_cast<const float*>(R1);
    float* part = reinterpret_cast<float*>(R0);
    int c = tid & 63, g = tid >> 6;
    float s = 0.f;
#pragma unroll
    for (int i = 0; i < 16; ++i) s += xaf[(g * 16 + i) * 64 + c];
    part[g * 64 + c] = s;
    __syncthreads();  // B12
    if (tid < 64) {
      float tt = 0.f;
#pragma unroll
      for (int gg = 0; gg < 8; ++gg) tt += part[gg * 64 + tid];
      gXa[((size_t)b * 15 + a) * 64 + tid] = tt * (1.f / 128.f);
    }
  }
}

// ---------------- k_head: per-batch head ----------------
__global__ __launch_bounds__(256) void k_head(const float* __restrict__ gXa,
                                              const float* __restrict__ W4,
                                              const float* __restrict__ b4,
                                              float* __restrict__ out) {
  __shared__ float xb[15 * 64];
  __shared__ float c2[15 * 16];
  __shared__ float mu[15];
  __shared__ float dinv[15];
  __shared__ float yy[15 * 64];
  __shared__ float zz[15 * 64];
  const int b = blockIdx.x;
  const int tid = threadIdx.x;
  for (int e = tid; e < 960; e += 256) xb[e] = gXa[(size_t)b * 960 + e];
  __syncthreads();
  if (tid < 15) {
    float s = 0.f;
    for (int c = 0; c < 64; ++c) s += xb[tid * 64 + c];
    mu[tid] = s * (1.f / 64.f);
  }
  __syncthreads();
  if (tid < 225) {
    int p = tid / 15, q = tid % 15;
    float s = 0.f;
    for (int c = 0; c < 64; ++c)
      s += (xb[p * 64 + c] - mu[p]) * (xb[q * 64 + c] - mu[q]);
    c2[p * 16 + q] = s;
  }
  __syncthreads();
  if (tid < 15) {
    float d = c2[tid * 16 + tid];
    dinv[tid] = d > 0.f ? (1.f / sqrtf(d)) : 0.f;
  }
  __syncthreads();
  if (tid < 225) {
    int p = tid / 15, q = tid % 15;
    float v = c2[p * 16 + q] * dinv[p] * dinv[q];
    v = fminf(1.f, fmaxf(-1.f, v));
    if (dinv[p] == 0.f || dinv[q] == 0.f) v = 0.f;
    c2[p * 16 + q] = v;
  }
  __syncthreads();
  for (int e = tid; e < 960; e += 256) {
    int p = e >> 6, c = e & 63;
    float s = 0.f;
    for (int q = 0; q < 15; ++q) s += c2[p * 16 + q] * xb[q * 64 + c];
    yy[e] = s;
  }
  __syncthreads();
  for (int e = tid; e < 960; e += 256) {
    int p = e >> 6, c = e & 63;
    float s = b4[c];
    for (int k = 0; k < 64; ++k) s += yy[p * 64 + k] * W4[k * 64 + c];
    zz[e] = leaky(s);
  }
  __syncthreads();
  if (tid < 64) {
    float m = -INFINITY;
    for (int p = 0; p < 15; ++p) m = fmaxf(m, zz[p * 64 + tid]);
    out[(size_t)b * 64 + tid] = m;
  }
}

extern "C" void kernel_launch(void* const* d_in, const int* in_sizes, int n_in,
                              void* d_out, int out_size, void* d_ws, size_t ws_size,
                              hipStream_t stream) {
  const float* x  = (const float*)d_in[0];
  const float* W1 = (const float*)d_in[1];
  const float* b1 = (const float*)d_in[2];
  const float* W2 = (const float*)d_in[3];
  const float* b2 = (const float*)d_in[4];
  const float* W3 = (const float*)d_in[5];
  const float* b3 = (const float*)d_in[6];
  const float* W4 = (const float*)d_in[7];
  const float* b4 = (const float*)d_in[8];
  float* out = (float*)d_out;

  char* ws = (char*)d_ws;
  unsigned short* xT   = (unsigned short*)ws;                 // 32*2048*128*2 = 16 MB
  unsigned short* XW1T = (unsigned short*)(ws + 16777216);    // 2 MB
  unsigned short* W1T  = (unsigned short*)(ws + 18874368);    // 1 MB
  unsigned short* W2T  = (unsigned short*)(ws + 19922944);    // 128 KB
  unsigned short* W3T  = (unsigned short*)(ws + 20054016);    // 32 KB
  float* gXa           = (float*)(ws + 20086784);             // 120 KB

  k_prep<<<2196, 256, 0, stream>>>(x, W1, W2, W3, W1T, W2T, W3T, xT);
  dim3 gx(8, 32);
  k_xw1<<<gx, 512, 0, stream>>>(x, W1T, XW1T);
  k_chain<<<480, 512, 0, stream>>>(xT, XW1T, W2T, W3T, b1, b2, b3, gXa);
  k_head<<<32, 256, 0, stream>>>(gXa, W4, b4, out);
}